// Round 14
// baseline (208.850 us; speedup 1.0000x reference)
//
#include <hip/hip_runtime.h>
#include <hip/hip_cooperative_groups.h>

namespace cg = cooperative_groups;

// TenHotEncodeLayer: out[n, x[n,j]] = 1.0, rest zeros.
// B=8192 rows, NUM_TOKENS=32000 cols (f32), K=10 indices/row.
//
// R14: ONE cooperative kernel, assembled ONLY from proven-fast parts:
//   pre-sweep : block b issues its 32 rows' index loads (first use after
//               sync -> 1000-iter sweep hides all latency)
//   sweep     : R7's exact load-free grid-stride fill (UNROLL=1, single
//               1MB sweeping window — the 6.4+ TB/s regime)
//   grid.sync : replaces {2nd launch + inter-dispatch drain}
//   scatter   : R13's dedup'd FULL-LINE writes (8 lanes x 16B = 128B line,
//               no RFO) from registers — no cold loads at the tail.
// R12's regression is explained as {x4 unroll + 4B RFO scatter}, not the
// sync itself; this isolates that. If this lands >=180, the coop fence is
// the cost and R13's two-dispatch structure is the roofline.

#define NUM_TOKENS 32000
#define KHOT 10
#define BLOCK 256
#define GRID 256                       // 1 block/CU -> coop co-residency
#define STRIDE (GRID * BLOCK)          // 65536 f32x4 = 1 MB window
#define TOTAL_F4 65536000              // 8192 * 8000
#define ITERS (TOTAL_F4 / STRIDE)      // exactly 1000
#define ROWS_PER_BLOCK 32              // 8 lanes per row x 32 rows = 256 thr

typedef float f32x4 __attribute__((ext_vector_type(4)));

__global__ __launch_bounds__(BLOCK) void tenhot_coop(
    const int* __restrict__ x, float* __restrict__ out, int B) {
    const int t    = threadIdx.x;
    const int b    = blockIdx.x;
    const int g    = t >> 3;           // row-group within block (0..31)
    const int lane = t & 7;            // 16B slice within the 128B line
    const int row  = b * ROWS_PER_BLOCK + g;
    const bool rowok = (row < B);

    // ---- pre-sweep: issue this row's 10 index loads (use deferred to
    // after sync; latency hidden under the sweep).
    int idx[KHOT];
    #pragma unroll
    for (int j = 0; j < KHOT; ++j)
        idx[j] = rowok ? x[row * KHOT + j] : -1;

    // ---- sweep: R7's exact load-free grid-stride zero fill.
    f32x4* __restrict__ out4 = (f32x4*)out;
    size_t i = (size_t)b * BLOCK + t;
    const f32x4 z = {0.f, 0.f, 0.f, 0.f};
    #pragma unroll 1
    for (int k = 0; k < ITERS; ++k) {
        out4[i] = z;
        i += (size_t)STRIDE;
    }

    // ---- grid-wide barrier: zeros globally visible before any ones.
    cg::this_grid().sync();

    // ---- scatter: R13's dedup'd full-line writes, straight from registers.
    if (rowok) {
        bool ok[KHOT];
        int  L [KHOT];                 // owning 128B line within the row
        #pragma unroll
        for (int j = 0; j < KHOT; ++j) {
            ok[j] = (idx[j] >= 0) && (idx[j] < NUM_TOKENS);   // mode="drop"
            L[j]  = ok[j] ? (idx[j] >> 5) : (-1 - j);         // distinct sentinels
        }
        #pragma unroll
        for (int j = 0; j < KHOT; ++j) {
            if (!ok[j]) continue;
            bool first = true;
            #pragma unroll
            for (int j2 = 0; j2 < KHOT; ++j2)
                if (j2 < j && L[j2] == L[j]) first = false;
            if (!first) continue;      // line already written by earlier j

            unsigned m = 0u;           // 32-bit hot mask for this line
            #pragma unroll
            for (int j2 = 0; j2 < KHOT; ++j2)
                if (L[j2] == L[j]) m |= 1u << (idx[j2] & 31); // dups OR same bit

            f32x4 v;                   // my 16B slice of the line
            #pragma unroll
            for (int u = 0; u < 4; ++u)
                v[u] = ((m >> (4 * lane + u)) & 1u) ? 1.0f : 0.0f;

            f32x4* dst = reinterpret_cast<f32x4*>(
                out + (size_t)row * NUM_TOKENS + (size_t)L[j] * 32);
            dst[lane] = v;             // 8 lanes x 16B = full line, no RFO
        }
    }
}

extern "C" void kernel_launch(void* const* d_in, const int* in_sizes, int n_in,
                              void* d_out, int out_size, void* d_ws, size_t ws_size,
                              hipStream_t stream) {
    const int* x = (const int*)d_in[0];
    float* out = (float*)d_out;
    int B = in_sizes[0] / KHOT;        // 8192
    void* args[] = {(void*)&x, (void*)&out, (void*)&B};
    hipLaunchCooperativeKernel((void*)tenhot_coop, dim3(GRID), dim3(BLOCK),
                               args, 0, stream);
}